// Round 8
// baseline (291.222 us; speedup 1.0000x reference)
//
#include <hip/hip_runtime.h>

#define NCH 2048
#define HW 196
#define NB 64
#define NOUT 48    // 32 downconv rows + 8 fc2 rows (cols 2048..4095) + 8 fc1 rows (cols 0..2047)
#define NCHUNK 16
#define CPC (NCH / NCHUNK)     // 128 channels per block
#define KS_PER_BLK (CPC / 32)  // 4 K-steps of 32 channels
#define KGTOT (NCH / 32)       // 64 global K-steps
#define NT 13                  // N-tiles of 16 (208 >= 196)
#define MT 3                   // M-tiles of 16 (48 outputs)
#define TILE_F (32 * HW)       // 6272 floats per K-step tile (25088 B, contiguous in x)
#define TILE_V4 (TILE_F / 4)   // 1568 float4
#define SLAB (NT * NOUT * 16)  // 9984 floats per-batch accumulator, layout [nt][ns16][o48]
#define SLAB8 (SLAB / 2)       // 4992 8-byte words
#define ROWSTRIDE (16 * NOUT)  // 768 floats per nt

typedef __attribute__((ext_vector_type(8))) short bf16x8;
typedef __attribute__((ext_vector_type(4))) float f32x4;
typedef __attribute__((ext_vector_type(4))) int i32x4;

__device__ __forceinline__ short f2bf(float f) {   // fp32->bf16 RNE (weights)
    unsigned int u = __float_as_uint(f);
    u = u + 0x7fffu + ((u >> 16) & 1u);
    return (short)(u >> 16);
}

// k-slot permutation (R7-verified correct): fragment element (kq, j) holds
// channel row R = kq*2 + (j&1) + (j>>1)*8; applied identically to A and B.
// ---------------------------------------------------------------------------
// Kernel 0: build afrag + zero the per-batch accumulator (ws is re-poisoned
// every iteration, and conv reduces into it with atomic fp32 adds).
// ---------------------------------------------------------------------------
__global__ void build_afrag(const float* __restrict__ down_w,
                            const float* __restrict__ fc_w,
                            bf16x8* __restrict__ afrag,
                            float* __restrict__ accb,
                            unsigned int* __restrict__ cnt) {
    int t = blockIdx.x * 256 + threadIdx.x;        // 48*256 = 12288
    if (blockIdx.x == 0 && threadIdx.x < NB) cnt[threadIdx.x] = 0;
    {   // zero NB*SLAB floats = 159744 float4, grid-stride
        float4* az = (float4*)accb;
        for (int i = t; i < NB * SLAB / 4; i += 12288)
            az[i] = (float4){0.f, 0.f, 0.f, 0.f};
    }
    if (t >= KGTOT * MT * 64) return;
    int lane = t & 63;
    int frag = t >> 6;
    int mt = frag % MT;
    int kg = frag / MT;
    int o = mt * 16 + (lane & 15);
    int kq = lane >> 4;
    bf16x8 v;
#pragma unroll
    for (int j = 0; j < 8; ++j) {
        int c = kg * 32 + kq * 2 + (j & 1) + ((j >> 1) << 3);   // permuted k-slot
        float w;
        if (o < 32)      w = down_w[o * NCH + c];
        else if (o < 40) w = fc_w[(o - 32) * (2 * NCH) + NCH + c];
        else             w = fc_w[(o - 40) * (2 * NCH) + c];
        v[j] = f2bf(w);
    }
    afrag[frag * 64 + lane] = v;
}

struct FinSM {
    float Ts[NOUT * HW];   // 37632 B
    float red[256];
    float gmp[32];
    float score[8];
    float xo[8];
    float sal[HW];
    float logit[8];
};

// ---------------------------------------------------------------------------
// R8: R7 with the cross-chunk fan-in moved from the serial finisher tail
// (R7 profile: occupancy 14.5% avg => ~40us tail with 64 blocks alive) into
// the parallel conv phase via hardware fp32 atomics (unsafeAtomicAdd ->
// global_atomic_add_f32, device-scope, executes at the coherence point).
// Finisher now reads ONE 40KB slab instead of eight. part traffic drops
// 20.4MB W + 20.4MB R -> 2.5MB each. NCHUNK 8->16 (1024 blocks) for more
// staging-latency overlap. Conv loop = R7-proven __syncthreads double-buffer.
// ---------------------------------------------------------------------------
__global__ __launch_bounds__(256) void conv_fin(const float* __restrict__ x,
                                                const bf16x8* __restrict__ afrag,
                                                const float* __restrict__ down_b,
                                                const float* __restrict__ fc_b,
                                                float* __restrict__ accb,
                                                unsigned int* __restrict__ cnt,
                                                float* __restrict__ out) {
    __shared__ union {
        float ldsx[2][TILE_F];   // 50176 B -> 3 blocks/CU
        FinSM fin;
    } sm;
    __shared__ int lastS;

    const int chunk = blockIdx.x;
    const int b = blockIdx.y;
    const int tid = threadIdx.x;
    const int wave = tid >> 6;
    const int lane = tid & 63;
    const int nsub = lane & 15;
    const int kq = lane >> 4;

    f32x4 acc[4][MT];
#pragma unroll
    for (int i = 0; i < 4; ++i)
#pragma unroll
        for (int m = 0; m < MT; ++m)
            acc[i][m] = (f32x4){0.f, 0.f, 0.f, 0.f};

    int pidx[4];
#pragma unroll
    for (int i = 0; i < 4; ++i) {
        int p = (wave + 4 * i) * 16 + nsub;
        pidx[i] = (p < HW) ? p : (HW - 1);   // clamp; junk cols skipped by finisher
    }

    const float* xtile0 = x + ((size_t)b * NCH + (size_t)chunk * CPC) * HW;

    auto stage = [&](int ks, int bb) {
        const float* g = xtile0 + (size_t)ks * TILE_F;
#pragma unroll
        for (int r = 0; r < 7; ++r) {              // ceil(1568/256)
            int q = r * 256 + tid;
            if (q < TILE_V4) {
                __builtin_amdgcn_global_load_lds(
                    (const __attribute__((address_space(1))) unsigned int*)(g + (size_t)q * 4),
                    (__attribute__((address_space(3))) unsigned int*)(&sm.ldsx[bb][(r * 256 + wave * 64) * 4]),
                    16, 0, 0);
            }
        }
    };

    stage(0, 0);

    for (int ks = 0; ks < KS_PER_BLK; ++ks) {
        __syncthreads();                  // barrier drains vmcnt -> tile ks visible
        if (ks + 1 < KS_PER_BLK) stage(ks + 1, (ks + 1) & 1);

        const int kg = chunk * KS_PER_BLK + ks;
        bf16x8 a0 = afrag[(kg * MT + 0) * 64 + lane];
        bf16x8 a1 = afrag[(kg * MT + 1) * 64 + lane];
        bf16x8 a2 = afrag[(kg * MT + 2) * 64 + lane];

        const float* base = &sm.ldsx[ks & 1][kq * 2 * HW];
#pragma unroll
        for (int i = 0; i < 4; ++i) {
            const float* bp = base + pidx[i];
            unsigned int u[8];
#pragma unroll
            for (int j = 0; j < 8; ++j)   // permuted rows (matches afrag k-perm)
                u[j] = __float_as_uint(bp[((j & 1) + ((j >> 1) << 3)) * HW]) + 0x8000u;
            i32x4 bi;
            bi[0] = (int)__builtin_amdgcn_perm(u[1], u[0], 0x07060302u);
            bi[1] = (int)__builtin_amdgcn_perm(u[3], u[2], 0x07060302u);
            bi[2] = (int)__builtin_amdgcn_perm(u[5], u[4], 0x07060302u);
            bi[3] = (int)__builtin_amdgcn_perm(u[7], u[6], 0x07060302u);
            bf16x8 bv = __builtin_bit_cast(bf16x8, bi);
            acc[i][0] = __builtin_amdgcn_mfma_f32_16x16x32_bf16(a0, bv, acc[i][0], 0, 0, 0);
            acc[i][1] = __builtin_amdgcn_mfma_f32_16x16x32_bf16(a1, bv, acc[i][1], 0, 0, 0);
            acc[i][2] = __builtin_amdgcn_mfma_f32_16x16x32_bf16(a2, bv, acc[i][2], 0, 0, 0);
        }
    }

    // Reduce into the per-batch slab with HW fp32 atomics (device scope,
    // executes at coherence point -> cross-XCD correct by construction).
    float* ab = accb + (size_t)b * SLAB;
#pragma unroll
    for (int i = 0; i < 4; ++i) {
        int nt = wave + 4 * i;
        if (nt < NT) {
            float* d = ab + nt * ROWSTRIDE + nsub * NOUT + kq * 4;
#pragma unroll
            for (int m = 0; m < MT; ++m)
#pragma unroll
                for (int r = 0; r < 4; ++r)
                    unsafeAtomicAdd(&d[m * 16 + r], acc[i][m][r]);
        }
    }

    __syncthreads();   // drains vmcnt: this block's atomics executed at L2
    if (tid == 0) {
        unsigned int old = __hip_atomic_fetch_add(&cnt[b], 1u,
                                                  __ATOMIC_RELAXED, __HIP_MEMORY_SCOPE_AGENT);
        int last = (old == NCHUNK - 1);
        if (last)   // acquire orders the slab reads below
            (void)__hip_atomic_load(&cnt[b], __ATOMIC_ACQUIRE, __HIP_MEMORY_SCOPE_AGENT);
        lastS = last;
    }
    __syncthreads();
    if (!lastS) return;

    // --- finish: last block of batch b; single-slab read (8B agent loads) ---
    {
        const unsigned long long* basep =
            (const unsigned long long*)(accb + (size_t)b * SLAB);
        for (int i8 = tid; i8 < SLAB8; i8 += 256) {
            unsigned long long u = __hip_atomic_load(
                basep + i8, __ATOMIC_RELAXED, __HIP_MEMORY_SCOPE_AGENT);
            union { unsigned long long u; float f[2]; } t;
            t.u = u;
            int idx = i8 * 2;
            int ntv = idx / ROWSTRIDE;
            int rem = idx - ntv * ROWSTRIDE;
            int ns = rem / NOUT;
            int o0 = rem - ns * NOUT;           // even
            int p = ntv * 16 + ns;
            if (p < HW) {
                sm.fin.Ts[o0 * HW + p] = t.f[0];
                sm.fin.Ts[(o0 + 1) * HW + p] = t.f[1];
            }
        }
    }
    __syncthreads();

    {   // GMP: 8 threads per output row
        int o = tid >> 3, s8 = tid & 7;
        float m = -1e30f;
        for (int p = s8; p < HW; p += 8) m = fmaxf(m, sm.fin.Ts[o * HW + p]);
        sm.fin.red[tid] = m;
    }
    __syncthreads();
    if (tid < 32) {
        float m = sm.fin.red[tid * 8];
#pragma unroll
        for (int j = 1; j < 8; ++j) m = fmaxf(m, sm.fin.red[tid * 8 + j]);
        sm.fin.gmp[tid] = m + down_b[tid];
    }
    __syncthreads();

    if (tid < 8)
        sm.fin.score[tid] = 0.25f * (sm.fin.gmp[4 * tid] + sm.fin.gmp[4 * tid + 1] +
                                     sm.fin.gmp[4 * tid + 2] + sm.fin.gmp[4 * tid + 3]);
    __syncthreads();

    if (tid < 8) {
        float m = -1e30f;
        for (int k = 0; k < 8; ++k) m = fmaxf(m, sm.fin.score[k]);
        float se = 0.f;
        for (int k = 0; k < 8; ++k) se += expf(sm.fin.score[k] - m);
        float xo = sm.fin.score[tid] - m - logf(se);
        sm.fin.xo[tid] = xo;
        out[b * 8 + tid] = xo;
    }
    __syncthreads();

    if (tid < HW) {
        float s = 0.f;
#pragma unroll
        for (int k = 0; k < 8; ++k) {
            float bs = down_b[4 * k] + down_b[4 * k + 1] +
                       down_b[4 * k + 2] + down_b[4 * k + 3];
            float rs = sm.fin.Ts[(4 * k) * HW + tid] + sm.fin.Ts[(4 * k + 1) * HW + tid] +
                       sm.fin.Ts[(4 * k + 2) * HW + tid] + sm.fin.Ts[(4 * k + 3) * HW + tid] + bs;
            s += sm.fin.xo[k] * rs;
        }
        sm.fin.sal[tid] = s * (1.f / 32.f);
    }
    __syncthreads();

    {   // logits: 32 threads per class
        int c = tid >> 5, s32 = tid & 31;
        float t = 0.f;
        for (int p = s32; p < HW; p += 32)
            t += sm.fin.Ts[(40 + c) * HW + p] + sm.fin.sal[p] * sm.fin.Ts[(32 + c) * HW + p];
        sm.fin.red[tid] = t;
    }
    __syncthreads();
    if (tid < 8) {
        float t = 0.f;
#pragma unroll
        for (int j = 0; j < 32; ++j) t += sm.fin.red[tid * 32 + j];
        sm.fin.logit[tid] = t * (1.f / 196.f) + fc_b[tid];
    }
    __syncthreads();

    if (tid < 8) {
        float m = -1e30f;
        for (int k = 0; k < 8; ++k) m = fmaxf(m, sm.fin.logit[k]);
        float se = 0.f;
        for (int k = 0; k < 8; ++k) se += expf(sm.fin.logit[k] - m);
        out[NB * 8 + b * 8 + tid] = sm.fin.logit[tid] - m - logf(se);
    }
}

extern "C" void kernel_launch(void* const* d_in, const int* in_sizes, int n_in,
                              void* d_out, int out_size, void* d_ws, size_t ws_size,
                              hipStream_t stream) {
    const float* x      = (const float*)d_in[0];
    const float* down_w = (const float*)d_in[1];
    const float* down_b = (const float*)d_in[2];
    const float* fc_w   = (const float*)d_in[3];
    const float* fc_b   = (const float*)d_in[4];
    float* out = (float*)d_out;

    bf16x8* afrag = (bf16x8*)d_ws;                                        // 192 KiB
    float* accb = (float*)((char*)d_ws + (size_t)KGTOT * MT * 64 * 16);   // 2.55 MiB
    unsigned int* cnt = (unsigned int*)((char*)accb + (size_t)NB * SLAB * 4);  // 256 B

    build_afrag<<<(KGTOT * MT * 64 + 255) / 256, 256, 0, stream>>>(down_w, fc_w, afrag, accb, cnt);
    conv_fin<<<dim3(NCHUNK, NB), 256, 0, stream>>>(x, afrag, down_b, fc_b, accb, cnt, out);
}

// Round 9
// 174.899 us; speedup vs baseline: 1.6651x; 1.6651x over previous
//
#include <hip/hip_runtime.h>

#define NCH 2048
#define HW 196
#define NB 64
#define NOUT 48    // 32 downconv rows + 8 fc2 rows (cols 2048..4095) + 8 fc1 rows (cols 0..2047)
#define NCHUNK 8
#define CPC (NCH / NCHUNK)     // 256 channels per block
#define KS_PER_BLK (CPC / 32)  // 8 K-steps of 32 channels
#define KGTOT (NCH / 32)       // 64 global K-steps
#define NT 13                  // N-tiles of 16 (208 >= 196)
#define MT 3                   // M-tiles of 16 (48 outputs)
#define TILE_F (32 * HW)       // 6272 floats per K-step tile (25088 B, contiguous in x)
#define TILE_V4 (TILE_F / 4)   // 1568 float4
#define TILE_PAD 7168          // 7*256 float4 -> uniform 7 loads/thread (pad absorbs tail)
#define SLAB (NT * NOUT * 16)  // 9984 floats per (b,chunk) slab, layout [nt][ns16][o48]
#define SLAB4 (SLAB / 4)       // 2496 float4
#define ROWSTRIDE (16 * NOUT)  // 768 floats per nt

typedef __attribute__((ext_vector_type(8))) short bf16x8;
typedef __attribute__((ext_vector_type(4))) float f32x4;
typedef __attribute__((ext_vector_type(4))) int i32x4;

__device__ __forceinline__ short f2bf(float f) {   // fp32->bf16 RNE (weights)
    unsigned int u = __float_as_uint(f);
    u = u + 0x7fffu + ((u >> 16) & 1u);
    return (short)(u >> 16);
}

// k-slot permutation (R7-verified): fragment element (kq, j) holds channel
// row R = kq*2 + (j&1) + (j>>1)*8; applied identically to A and B.
// ---------------------------------------------------------------------------
__global__ void build_afrag(const float* __restrict__ down_w,
                            const float* __restrict__ fc_w,
                            bf16x8* __restrict__ afrag) {
    int t = blockIdx.x * 256 + threadIdx.x;        // 48*256 = 12288
    if (t >= KGTOT * MT * 64) return;
    int lane = t & 63;
    int frag = t >> 6;
    int mt = frag % MT;
    int kg = frag / MT;
    int o = mt * 16 + (lane & 15);
    int kq = lane >> 4;
    bf16x8 v;
#pragma unroll
    for (int j = 0; j < 8; ++j) {
        int c = kg * 32 + kq * 2 + (j & 1) + ((j >> 1) << 3);   // permuted k-slot
        float w;
        if (o < 32)      w = down_w[o * NCH + c];
        else if (o < 40) w = fc_w[(o - 32) * (2 * NCH) + NCH + c];
        else             w = fc_w[(o - 40) * (2 * NCH) + c];
        v[j] = f2bf(w);
    }
    afrag[frag * 64 + lane] = v;
}

// ---------------------------------------------------------------------------
// R9 conv: 3-buffer counted-vmcnt pipeline (R5 machinery, exonerated by the
// R6 bisect -- the sc1 asm alone reproduced the failure). Uniform padded
// staging makes vmcnt(7) exact per wave. Iteration order {vmcnt; barrier;
// stage(ks+2); compute(ks)} is race-free: at the barrier, every wave's tile-ks
// loads are retired AND every wave finished reading buf[(ks-1)%3]=buf[(ks+2)%3].
// Slab stores are PLAIN dwordx4 -- cross-XCD visibility comes from the kernel
// boundary (stream order), the ledger's proven-cheap sync. No atomics anywhere.
// ---------------------------------------------------------------------------
__global__ __launch_bounds__(256, 1) void conv(const float* __restrict__ x,
                                               const bf16x8* __restrict__ afrag,
                                               float* __restrict__ part) {
    __shared__ float ldsx[3][TILE_PAD];   // 86016 B -> 1 block/CU

    const int chunk = blockIdx.x;
    const int b = blockIdx.y;
    const int tid = threadIdx.x;
    const int wave = tid >> 6;
    const int lane = tid & 63;
    const int nsub = lane & 15;
    const int kq = lane >> 4;

    f32x4 acc[4][MT];
#pragma unroll
    for (int i = 0; i < 4; ++i)
#pragma unroll
        for (int m = 0; m < MT; ++m)
            acc[i][m] = (f32x4){0.f, 0.f, 0.f, 0.f};

    int pidx[4];
#pragma unroll
    for (int i = 0; i < 4; ++i) {
        int p = (wave + 4 * i) * 16 + nsub;
        pidx[i] = (p < HW) ? p : (HW - 1);   // clamp; junk cols skipped by finish
    }

    const float* xtile0 = x + ((size_t)b * NCH + (size_t)chunk * CPC) * HW;

    // UNIFORM staging: exactly 7 global_load_lds per thread per tile.
    auto stage = [&](int ks, int bb) {
        const float* g = xtile0 + (size_t)ks * TILE_F;
#pragma unroll
        for (int r = 0; r < 7; ++r) {
            int q = r * 256 + tid;
            int qc = (q < TILE_V4) ? q : (TILE_V4 - 1);   // per-lane source clamp
            __builtin_amdgcn_global_load_lds(
                (const __attribute__((address_space(1))) unsigned int*)(g + (size_t)qc * 4),
                (__attribute__((address_space(3))) unsigned int*)(&ldsx[bb][(r * 256 + wave * 64) * 4]),
                16, 0, 0);
        }
    };

    // Hoist all afrag fragments to registers (in-loop loads would add
    // non-constant terms to the wave's vmcnt bookkeeping).
    bf16x8 areg[KS_PER_BLK][MT];
#pragma unroll
    for (int ks = 0; ks < KS_PER_BLK; ++ks)
#pragma unroll
        for (int m = 0; m < MT; ++m)
            areg[ks][m] = afrag[((chunk * KS_PER_BLK + ks) * MT + m) * 64 + lane];
    __builtin_amdgcn_sched_barrier(0);   // pin: areg loads issue before stages

    stage(0, 0);
    stage(1, 1);

#pragma unroll
    for (int ks = 0; ks < KS_PER_BLK; ++ks) {
        // entry: tiles ks (7/wave) and ks+1 (7/wave, if exists) outstanding
        if (ks < KS_PER_BLK - 1) asm volatile("s_waitcnt vmcnt(7)" ::: "memory");
        else                     asm volatile("s_waitcnt vmcnt(0)" ::: "memory");
        __builtin_amdgcn_s_barrier();    // all waves: tile ks landed, buf[(ks+2)%3] free
        if (ks + 2 < KS_PER_BLK) stage(ks + 2, (ks + 2) % 3);

        const float* base = &ldsx[ks % 3][kq * 2 * HW];
#pragma unroll
        for (int i = 0; i < 4; ++i) {
            const float* bp = base + pidx[i];
            unsigned int u[8];
#pragma unroll
            for (int j = 0; j < 8; ++j)   // permuted rows (matches afrag k-perm)
                u[j] = __float_as_uint(bp[((j & 1) + ((j >> 1) << 3)) * HW]) + 0x8000u;
            i32x4 bi;
            bi[0] = (int)__builtin_amdgcn_perm(u[1], u[0], 0x07060302u);
            bi[1] = (int)__builtin_amdgcn_perm(u[3], u[2], 0x07060302u);
            bi[2] = (int)__builtin_amdgcn_perm(u[5], u[4], 0x07060302u);
            bi[3] = (int)__builtin_amdgcn_perm(u[7], u[6], 0x07060302u);
            bf16x8 bv = __builtin_bit_cast(bf16x8, bi);
            acc[i][0] = __builtin_amdgcn_mfma_f32_16x16x32_bf16(areg[ks][0], bv, acc[i][0], 0, 0, 0);
            acc[i][1] = __builtin_amdgcn_mfma_f32_16x16x32_bf16(areg[ks][1], bv, acc[i][1], 0, 0, 0);
            acc[i][2] = __builtin_amdgcn_mfma_f32_16x16x32_bf16(areg[ks][2], bv, acc[i][2], 0, 0, 0);
        }
    }

    // plain coalesced dwordx4 stores, layout [nt][ns16][o48]
    float* pb = part + (size_t)(b * NCHUNK + chunk) * SLAB;
#pragma unroll
    for (int i = 0; i < 4; ++i) {
        int nt = wave + 4 * i;
        if (nt < NT) {
            float* d = pb + nt * ROWSTRIDE + nsub * NOUT + kq * 4;
#pragma unroll
            for (int m = 0; m < MT; ++m)
                *(f32x4*)(d + m * 16) = acc[i][m];
        }
    }
}

// ---------------------------------------------------------------------------
// R9 reduce: full-chip fan-in (624 blocks) -- 20.4MB read at device BW ~3us,
// vs R7's 64-block tail at 25% of chip BW (~33us). Plain cached loads.
// ---------------------------------------------------------------------------
__global__ __launch_bounds__(256) void reduce_part(const float4* __restrict__ part4,
                                                   float4* __restrict__ tred4) {
    int t = blockIdx.x * 256 + threadIdx.x;
    if (t >= NB * SLAB4) return;
    int b = t / SLAB4;
    int r = t - b * SLAB4;
    const float4* p = part4 + (size_t)b * NCHUNK * SLAB4 + r;
    float4 s = p[0];
#pragma unroll
    for (int ch = 1; ch < NCHUNK; ++ch) {
        float4 v = p[(size_t)ch * SLAB4];
        s.x += v.x; s.y += v.y; s.z += v.z; s.w += v.w;
    }
    tred4[t] = s;
}

// ---------------------------------------------------------------------------
// R9 finish: one block per batch; reads the 40KB reduced slab (LLC-hot,
// plain float4 loads) + R7-proven parallelized epilogue.
// ---------------------------------------------------------------------------
__global__ __launch_bounds__(256) void finish(const float4* __restrict__ tred4,
                                              const float* __restrict__ down_b,
                                              const float* __restrict__ fc_b,
                                              float* __restrict__ out) {
    const int b = blockIdx.x;
    const int tid = threadIdx.x;
    __shared__ float Ts[NOUT * HW];
    __shared__ float red[256];
    __shared__ float gmpS[32];
    __shared__ float scoreS[8];
    __shared__ float xoS[8];
    __shared__ float salS[HW];
    __shared__ float logitS[8];

    {
        const float4* basep = tred4 + (size_t)b * SLAB4;
        for (int i4 = tid; i4 < SLAB4; i4 += 256) {
            float4 s = basep[i4];
            int idx = i4 * 4;
            int ntv = idx / ROWSTRIDE;
            int rem = idx - ntv * ROWSTRIDE;
            int ns = rem / NOUT;
            int o0 = rem - ns * NOUT;           // multiple of 4
            int p = ntv * 16 + ns;
            if (p < HW) {
                Ts[o0 * HW + p] = s.x;
                Ts[(o0 + 1) * HW + p] = s.y;
                Ts[(o0 + 2) * HW + p] = s.z;
                Ts[(o0 + 3) * HW + p] = s.w;
            }
        }
    }
    __syncthreads();

    {   // GMP: 8 threads per output row
        int o = tid >> 3, s8 = tid & 7;
        float m = -1e30f;
        for (int p = s8; p < HW; p += 8) m = fmaxf(m, Ts[o * HW + p]);
        red[tid] = m;
    }
    __syncthreads();
    if (tid < 32) {
        float m = red[tid * 8];
#pragma unroll
        for (int j = 1; j < 8; ++j) m = fmaxf(m, red[tid * 8 + j]);
        gmpS[tid] = m + down_b[tid];
    }
    __syncthreads();

    if (tid < 8)
        scoreS[tid] = 0.25f * (gmpS[4 * tid] + gmpS[4 * tid + 1] +
                               gmpS[4 * tid + 2] + gmpS[4 * tid + 3]);
    __syncthreads();

    if (tid < 8) {
        float m = -1e30f;
        for (int k = 0; k < 8; ++k) m = fmaxf(m, scoreS[k]);
        float se = 0.f;
        for (int k = 0; k < 8; ++k) se += expf(scoreS[k] - m);
        float xo = scoreS[tid] - m - logf(se);
        xoS[tid] = xo;
        out[b * 8 + tid] = xo;
    }
    __syncthreads();

    if (tid < HW) {
        float s = 0.f;
#pragma unroll
        for (int k = 0; k < 8; ++k) {
            float bs = down_b[4 * k] + down_b[4 * k + 1] +
                       down_b[4 * k + 2] + down_b[4 * k + 3];
            float rs = Ts[(4 * k) * HW + tid] + Ts[(4 * k + 1) * HW + tid] +
                       Ts[(4 * k + 2) * HW + tid] + Ts[(4 * k + 3) * HW + tid] + bs;
            s += xoS[k] * rs;
        }
        salS[tid] = s * (1.f / 32.f);
    }
    __syncthreads();

    {   // logits: 32 threads per class
        int c = tid >> 5, s32 = tid & 31;
        float t = 0.f;
        for (int p = s32; p < HW; p += 32)
            t += Ts[(40 + c) * HW + p] + salS[p] * Ts[(32 + c) * HW + p];
        red[tid] = t;
    }
    __syncthreads();
    if (tid < 8) {
        float t = 0.f;
#pragma unroll
        for (int j = 0; j < 32; ++j) t += red[tid * 32 + j];
        logitS[tid] = t * (1.f / 196.f) + fc_b[tid];
    }
    __syncthreads();

    if (tid < 8) {
        float m = -1e30f;
        for (int k = 0; k < 8; ++k) m = fmaxf(m, logitS[k]);
        float se = 0.f;
        for (int k = 0; k < 8; ++k) se += expf(logitS[k] - m);
        out[NB * 8 + b * 8 + tid] = logitS[tid] - m - logf(se);
    }
}

extern "C" void kernel_launch(void* const* d_in, const int* in_sizes, int n_in,
                              void* d_out, int out_size, void* d_ws, size_t ws_size,
                              hipStream_t stream) {
    const float* x      = (const float*)d_in[0];
    const float* down_w = (const float*)d_in[1];
    const float* down_b = (const float*)d_in[2];
    const float* fc_w   = (const float*)d_in[3];
    const float* fc_b   = (const float*)d_in[4];
    float* out = (float*)d_out;

    bf16x8* afrag = (bf16x8*)d_ws;                                         // 192 KiB
    float* part = (float*)((char*)d_ws + (size_t)KGTOT * MT * 64 * 16);    // 20.4 MiB
    float* tred = (float*)((char*)part + (size_t)NB * NCHUNK * SLAB * 4);  // 2.55 MiB

    build_afrag<<<(KGTOT * MT * 64 + 255) / 256, 256, 0, stream>>>(down_w, fc_w, afrag);
    conv<<<dim3(NCHUNK, NB), 256, 0, stream>>>(x, afrag, part);
    reduce_part<<<(NB * SLAB4 + 255) / 256, 256, 0, stream>>>((const float4*)part, (float4*)tred);
    finish<<<NB, 256, 0, stream>>>((const float4*)tred, down_b, fc_b, out);
}